// Round 7
// baseline (762.681 us; speedup 1.0000x reference)
//
#include <hip/hip_runtime.h>

typedef short bf16x8 __attribute__((ext_vector_type(8)));
typedef _Float16 f16x8 __attribute__((ext_vector_type(8)));
typedef float f32x4 __attribute__((ext_vector_type(4)));

__device__ __forceinline__ short f2h(float f) {
  _Float16 h = (_Float16)f;
  return __builtin_bit_cast(short, h);
}
__device__ __forceinline__ float h2f(short s) {
  return (float)__builtin_bit_cast(_Float16, s);
}

__device__ __forceinline__ void gload16(const void* g, void* lds) {
  __builtin_amdgcn_global_load_lds(
      (const __attribute__((address_space(1))) unsigned*)g,
      (__attribute__((address_space(3))) unsigned*)lds, 16, 0, 0);
}

// ---------------------------------------------------------------------------
// 256xBN tile GEMM, C = A @ B^T (f16, K contiguous), 512 thr = 8 waves (2Mx4N).
// K-sliced phase pipeline: NP = K/32 phases; chunk(P) = {A[:,32 k-slice P],
// B[:,slice P]} in one of 4 LDS slots (slot = P&3). Phase P:
//   issue stage(P+2) -> vmcnt(8) [chunks P+1,P+2 in flight; P complete]
//   -> s_barrier -> 12 ds_read_b128 -> setprio(1) 8xNF MFMA setprio(0).
// Slot overwrite safety: stage(P+2) issues only after barrier P-? ordering
// guarantees all waves completed chunk(P-2) reads (one barrier per phase).
// LDS XOR-swizzle (16B granule ^ (row&3)) on global src + ds_read (rule #21).
// NF: 4 -> BN=256 (4 gloads/thr/stage), 2 -> BN=128 (3 gloads/thr/stage).
// OMODE: 0=f32 out, 1=f16 out. BIAS_MODE: 0 none, 1 bias[col], 2 bias[row].
// RES: add fp32 resid (stride sR per blockIdx.z).
// ---------------------------------------------------------------------------
template <int NF, int K, int OMODE, int BIAS_MODE, int RES>
__global__ __launch_bounds__(512, 2) void gemmp(
    const short* __restrict__ A, int lda, long sA,
    const short* __restrict__ B, int ldb, long sB,
    void* __restrict__ Cv, int ldc, long sC,
    const float* __restrict__ bias, const float* __restrict__ resid, long sR) {
  constexpr int ACH = 16384;       // A bytes per chunk (256 x 32 f16)
  constexpr int BCH = NF * 4096;   // B bytes per chunk (NF*64 x 32 f16)
  constexpr int CH = ACH + BCH;    // chunk slot stride
  constexpr int NP = K / 32;       // number of phases
  __shared__ char lds[4 * CH];

  A += (size_t)blockIdx.z * sA;
  B += (size_t)blockIdx.z * sB;
  char* Cb = (char*)Cv + (size_t)blockIdx.z * sC * (OMODE == 0 ? 4 : 2);
  const float* res = resid ? resid + (size_t)blockIdx.z * sR : nullptr;

  const int tid = threadIdx.x;
  const int wid = tid >> 6, lane = tid & 63;
  const int wr = wid >> 2, wc = wid & 3;  // wave grid 2 (M) x 4 (N)
  const int fr = lane & 15, fq = lane >> 4;
  const size_t bm = (size_t)blockIdx.y * 256;
  const size_t bn = (size_t)blockIdx.x * (NF * 64);

  const char* Ag = (const char*)A;
  const char* Bg = (const char*)B;

  // ds_read byte offsets within a chunk slot (row stride 64B, swizzled)
  const int swz = (fr & 3) << 4;
  int aoff[8], boff[NF];
#pragma unroll
  for (int m = 0; m < 8; m++)
    aoff[m] = (wr * 128 + m * 16 + fr) * 64 + ((fq * 16) ^ swz);
#pragma unroll
  for (int n = 0; n < NF; n++)
    boff[n] = ACH + (wc * NF * 16 + n * 16 + fr) * 64 + ((fq * 16) ^ swz);

  f32x4 acc[8][NF];
#pragma unroll
  for (int m = 0; m < 8; m++)
#pragma unroll
    for (int n = 0; n < NF; n++) acc[m][n] = (f32x4){0.f, 0.f, 0.f, 0.f};

  // stage chunk p into slot p&3 (linear LDS dest, inverse-swizzled global src)
  auto stage = [&](int p) {
    char* s = &lds[(p & 3) * CH];
    const int ktB = p * 64;  // byte offset along K (32 f16)
#pragma unroll
    for (int i = 0; i < 2; ++i) {  // A: 1024 granules, 2 per thread
      const int gi = (wid * 2 + i) * 64 + lane;
      const int r = gi >> 2, c = gi & 3;
      gload16(Ag + (size_t)(bm + r) * (size_t)(lda * 2) + ktB +
                  ((c ^ (r & 3)) * 16),
              s + (wid * 2 + i) * 1024);
    }
    if constexpr (NF == 4) {
#pragma unroll
      for (int i = 0; i < 2; ++i) {  // B: 1024 granules, 2 per thread
        const int gi = (wid * 2 + i) * 64 + lane;
        const int r = gi >> 2, c = gi & 3;
        gload16(Bg + (size_t)(bn + r) * (size_t)(ldb * 2) + ktB +
                    ((c ^ (r & 3)) * 16),
                s + ACH + (wid * 2 + i) * 1024);
      }
    } else {
      const int gi = wid * 64 + lane;  // B: 512 granules, 1 per thread
      const int r = gi >> 2, c = gi & 3;
      gload16(Bg + (size_t)(bn + r) * (size_t)(ldb * 2) + ktB +
                  ((c ^ (r & 3)) * 16),
              s + ACH + wid * 1024);
    }
  };

  stage(0);
  stage(1);
#pragma unroll 4
  for (int P = 0; P < NP; ++P) {
    if (P + 2 < NP) stage(P + 2);
    __builtin_amdgcn_sched_barrier(0);
    if (P + 2 < NP) {
      if constexpr (NF == 4) asm volatile("s_waitcnt vmcnt(8)");
      else                   asm volatile("s_waitcnt vmcnt(6)");
    } else if (P + 1 < NP) {
      if constexpr (NF == 4) asm volatile("s_waitcnt vmcnt(4)");
      else                   asm volatile("s_waitcnt vmcnt(3)");
    } else {
      asm volatile("s_waitcnt vmcnt(0)");
    }
    __builtin_amdgcn_sched_barrier(0);
    __builtin_amdgcn_s_barrier();  // chunk P resident block-wide
    __builtin_amdgcn_sched_barrier(0);
    {
      const char* s = &lds[(P & 3) * CH];
      f16x8 ar[8], br[NF];
#pragma unroll
      for (int m = 0; m < 8; m++) ar[m] = *(const f16x8*)(s + aoff[m]);
#pragma unroll
      for (int n = 0; n < NF; n++) br[n] = *(const f16x8*)(s + boff[n]);
      __builtin_amdgcn_s_setprio(1);
#pragma unroll
      for (int m = 0; m < 8; m++)
#pragma unroll
        for (int n = 0; n < NF; n++)
          acc[m][n] = __builtin_amdgcn_mfma_f32_16x16x32_f16(ar[m], br[n],
                                                             acc[m][n], 0, 0, 0);
      __builtin_amdgcn_s_setprio(0);
    }
    __builtin_amdgcn_sched_barrier(0);
  }

#pragma unroll
  for (int m = 0; m < 8; m++) {
    const size_t row0 = bm + wr * 128 + m * 16 + fq * 4;
#pragma unroll
    for (int n = 0; n < NF; n++) {
      const size_t col = bn + wc * NF * 16 + n * 16 + fr;
      float bcol = (BIAS_MODE == 1) ? bias[col] : 0.f;
#pragma unroll
      for (int r = 0; r < 4; r++) {
        float val = acc[m][n][r];
        const size_t row = row0 + r;
        const size_t idx = row * (size_t)ldc + col;
        if (BIAS_MODE == 1) val += bcol;
        if (BIAS_MODE == 2) val += bias[row];
        if (RES) val += res[idx];
        if (OMODE == 0)
          ((float*)Cb)[idx] = val;
        else
          ((short*)Cb)[idx] = f2h(val);
      }
    }
  }
}

__global__ __launch_bounds__(256) void cvt_f32_f16(const float* __restrict__ s,
                                                   short* __restrict__ d, int n) {
  int i = (blockIdx.x * 256 + threadIdx.x) * 8;
  if (i >= n) return;
  const float4 a = *(const float4*)(s + i);
  const float4 b = *(const float4*)(s + i + 4);
  bf16x8 o;
  o[0] = f2h(a.x); o[1] = f2h(a.y); o[2] = f2h(a.z); o[3] = f2h(a.w);
  o[4] = f2h(b.x); o[5] = f2h(b.y); o[6] = f2h(b.z); o[7] = f2h(b.w);
  *(bf16x8*)(d + i) = o;
}

// one block per row of 4096 f16 scores; fp32 softmax; in-place f16 probs
__global__ __launch_bounds__(256) void softmax_rows(short* __restrict__ S) {
  const size_t row = blockIdx.x;
  short* rp = S + row * 4096;
  const int tid = threadIdx.x;
  const int lane = tid & 63, wid = tid >> 6;
  float v[16];
#pragma unroll
  for (int c = 0; c < 2; c++) {
    bf16x8 xv = *(const bf16x8*)(rp + (c * 256 + tid) * 8);
#pragma unroll
    for (int j = 0; j < 8; j++) v[c * 8 + j] = h2f(xv[j]);
  }
  float m = v[0];
#pragma unroll
  for (int i = 1; i < 16; i++) m = fmaxf(m, v[i]);
#pragma unroll
  for (int off = 32; off >= 1; off >>= 1) m = fmaxf(m, __shfl_xor(m, off));
  __shared__ float red[8];
  if (lane == 0) red[wid] = m;
  __syncthreads();
  m = fmaxf(fmaxf(red[0], red[1]), fmaxf(red[2], red[3]));
  float s = 0.f;
#pragma unroll
  for (int i = 0; i < 16; i++) {
    v[i] = __expf(v[i] - m);
    s += v[i];
  }
#pragma unroll
  for (int off = 32; off >= 1; off >>= 1) s += __shfl_xor(s, off);
  if (lane == 0) red[4 + wid] = s;
  __syncthreads();
  s = (red[4] + red[5]) + (red[6] + red[7]);
  const float rs = 1.0f / s;
#pragma unroll
  for (int c = 0; c < 2; c++) {
    bf16x8 o;
#pragma unroll
    for (int j = 0; j < 8; j++) o[j] = f2h(v[c * 8 + j] * rs);
    *(bf16x8*)(rp + (c * 256 + tid) * 8) = o;
  }
}

extern "C" void kernel_launch(void* const* d_in, const int* in_sizes, int n_in,
                              void* d_out, int out_size, void* d_ws,
                              size_t ws_size, hipStream_t stream) {
  const float* x   = (const float*)d_in[0];
  const float* thw = (const float*)d_in[1];
  const float* thb = (const float*)d_in[2];
  const float* phw = (const float*)d_in[3];
  const float* phb = (const float*)d_in[4];
  const float* gw  = (const float*)d_in[5];
  const float* gbi = (const float*)d_in[6];
  const float* Ww  = (const float*)d_in[7];
  const float* Wb  = (const float*)d_in[8];
  float* out = (float*)d_out;

  // B=4, N=4096, D=2048, E=1024.  ws footprint 184,557,568 B (proven size)
  char* ws = (char*)d_ws;
  short* xf   = (short*)(ws);                // 67,108,864 B (16384x2048 f16)
  short* wcat = (short*)(ws + 67108864);     //  8,388,608 B (theta|phi 2048x2048)
  short* gwb  = (short*)(ws + 75497472);     //  4,194,304 B (1024x2048)
  short* wWb  = (short*)(ws + 79691776);     //  4,194,304 B (2048x1024)
  float* bc   = (float*)(ws + 83886080);     //  8,192 B (theta_b|phi_b)
  short* tpf  = (short*)(ws + 83894272);     // 67,108,864 B (theta|phi; later y)
  short* gT   = (short*)(ws + 151003136);    // 33,554,432 B (4x1024x4096)
  short* sc   = (short*)(ws);                // 67,108,864 B (2x4096x4096, over xf)

  // 1) fp32 -> f16 conversions
  cvt_f32_f16<<<16384, 256, 0, stream>>>(x, xf, 33554432);
  cvt_f32_f16<<<1024, 256, 0, stream>>>(thw, wcat, 2097152);
  cvt_f32_f16<<<1024, 256, 0, stream>>>(phw, wcat + 2097152, 2097152);
  cvt_f32_f16<<<1024, 256, 0, stream>>>(gw, gwb, 2097152);
  cvt_f32_f16<<<1024, 256, 0, stream>>>(Ww, wWb, 2097152);
  hipMemcpyAsync(bc, thb, 4096, hipMemcpyDeviceToDevice, stream);
  hipMemcpyAsync(bc + 1024, phb, 4096, hipMemcpyDeviceToDevice, stream);

  // 2) proj: [theta|phi] = x @ wcat^T + bias   (16384 x 2048, K=2048)
  gemmp<4, 2048, 1, 1, 0><<<dim3(8, 64, 1), 512, 0, stream>>>(
      xf, 2048, 0L, wcat, 2048, 0L, tpf, 2048, 0L, bc, nullptr, 0L);

  // 3) gT[b] = g_w @ x_b^T + g_b[row]   (1024 x 4096 per batch, K=2048)
  gemmp<4, 2048, 1, 2, 0><<<dim3(16, 4, 4), 512, 0, stream>>>(
      gwb, 2048, 0L, xf, 2048, 8388608L, gT, 4096, 4194304L, gbi, nullptr, 0L);

  // 4) per batch-PAIR p: scores(z=2) -> softmax -> y(z=2) -> z(z=2)
  //    sc pair overlays xf (dead after gT); y overwrites consumed theta/phi.
  for (int p = 0; p < 2; ++p) {
    const short* tp = tpf + (size_t)p * 16777216;
    gemmp<4, 1024, 1, 0, 0><<<dim3(16, 16, 2), 512, 0, stream>>>(
        tp, 2048, 8388608L, tp + 1024, 2048, 8388608L,
        sc, 4096, 16777216L, nullptr, nullptr, 0L);
    softmax_rows<<<8192, 256, 0, stream>>>(sc);
    short* yp = tpf + (size_t)p * 16777216;  // pair-p theta/phi now dead
    gemmp<2, 4096, 1, 0, 0><<<dim3(8, 16, 2), 512, 0, stream>>>(
        sc, 4096, 16777216L, gT + (size_t)p * 8388608, 4096, 4194304L,
        yp, 1024, 4194304L, nullptr, nullptr, 0L);
    gemmp<4, 1024, 0, 1, 1><<<dim3(8, 16, 2), 512, 0, stream>>>(
        yp, 1024, 4194304L, wWb, 1024, 0L,
        out + (size_t)p * 16777216, 2048, 8388608L,
        Wb, x + (size_t)p * 16777216, 8388608L);
  }
}

// Round 8
// 755.192 us; speedup vs baseline: 1.0099x; 1.0099x over previous
//
#include <hip/hip_runtime.h>

typedef short bf16x8 __attribute__((ext_vector_type(8)));
typedef _Float16 f16x8 __attribute__((ext_vector_type(8)));
typedef float f32x4 __attribute__((ext_vector_type(4)));

__device__ __forceinline__ short f2h(float f) {
  _Float16 h = (_Float16)f;
  return __builtin_bit_cast(short, h);
}
__device__ __forceinline__ float h2f(short s) {
  return (float)__builtin_bit_cast(_Float16, s);
}

__device__ __forceinline__ void gload16(const void* g, void* lds) {
  __builtin_amdgcn_global_load_lds(
      (const __attribute__((address_space(1))) unsigned*)g,
      (__attribute__((address_space(3))) unsigned*)lds, 16, 0, 0);
}

// LDS swizzle within a chunk region (64B logical rows):
//   phys = F(a) = a ^ ((a>>2) & 0x70)      [b4^=a6, b5^=a7, b6^=a8]
//   F^-1(s)     = s ^ ((((s>>2)^(s>>4)) & 0x10) | ((s>>2) & 0x60))
// 16-lane fragment groups land 2 lanes/16B-slot uniformly -> conflict-free.
__device__ __forceinline__ int swzF(int a) { return a ^ ((a >> 2) & 0x70); }
__device__ __forceinline__ int swzI(int s) {
  return s ^ ((((s >> 2) ^ (s >> 4)) & 0x10) | ((s >> 2) & 0x60));
}

// ---------------------------------------------------------------------------
// 256xBN tile GEMM, C = A @ B^T (f16, K contiguous), 512 thr = 8 waves (2Mx4N).
// K=32 chunk pipeline, 4 LDS slots, register read-ahead:
//  phase P: stage(P+2) -> vmcnt(4) [own stage(P+1) retired, P+2 in flight]
//           -> s_barrier [chunk P+1 resident block-wide]
//           -> ds_read chunk P+1 into NEXT frag set (no in-phase wait)
//           -> 32 MFMA on CURRENT frag set (loaded last phase).
// Slot safety: stage(P+2) overwrites chunk P-2, whose reads (phase P-3) are
// lgkm-confirmed before MFMA(P-2) which precedes barrier(P-1) < stage issue.
// ---------------------------------------------------------------------------
template <int NF, int K, int OMODE, int BIAS_MODE, int RES>
__global__ __launch_bounds__(512, 2) void gemmp(
    const short* __restrict__ A, int lda, long sA,
    const short* __restrict__ B, int ldb, long sB,
    void* __restrict__ Cv, int ldc, long sC,
    const float* __restrict__ bias, const float* __restrict__ resid, long sR) {
  constexpr int ACH = 16384;      // A chunk bytes (256 rows x 64B)
  constexpr int BCH = NF * 4096;  // B chunk bytes (NF*64 rows x 64B)
  constexpr int CH = ACH + BCH;
  constexpr int NP = K / 32;
  __shared__ __align__(1024) char lds[4 * CH];

  A += (size_t)blockIdx.z * sA;
  B += (size_t)blockIdx.z * sB;
  char* Cb = (char*)Cv + (size_t)blockIdx.z * sC * (OMODE == 0 ? 4 : 2);
  const float* res = resid ? resid + (size_t)blockIdx.z * sR : nullptr;

  const int tid = threadIdx.x;
  const int wid = tid >> 6, lane = tid & 63;
  const int wr = wid >> 2, wc = wid & 3;  // wave grid 2 (M) x 4 (N)
  const int fr = lane & 15, fq = lane >> 4;
  const size_t bm = (size_t)blockIdx.y * 256;
  const size_t bn = (size_t)blockIdx.x * (NF * 64);

  const char* Ag = (const char*)A;
  const char* Bg = (const char*)B;
  const int ldaB = lda * 2, ldbB = ldb * 2;

  // staging: dest granule d (linear, wave-uniform base + lane*16); source is
  // inverse-swizzled so that reads with F() see logical row-major data.
  int offA[2], offB[2], dstA[2], dstB[2];
#pragma unroll
  for (int i = 0; i < 2; ++i) {
    const int d = ((wid * 2 + i) * 64 + lane) * 16;
    const int a = swzI(d);
    offA[i] = (int)(bm * 0) + (a >> 6) * ldaB + (a & 63);  // row*ldaB + col
    dstA[i] = (wid * 2 + i) * 1024;
  }
  const size_t Abase = bm * (size_t)ldaB;
  size_t Bbase = bn * (size_t)ldbB;
  if constexpr (NF == 4) {
#pragma unroll
    for (int i = 0; i < 2; ++i) {
      const int d = ((wid * 2 + i) * 64 + lane) * 16;
      const int a = swzI(d);
      offB[i] = (a >> 6) * ldbB + (a & 63);
      dstB[i] = ACH + (wid * 2 + i) * 1024;
    }
  } else {
    const int d = (wid * 64 + lane) * 16;
    const int a = swzI(d);
    offB[0] = (a >> 6) * ldbB + (a & 63);
    dstB[0] = ACH + wid * 1024;
  }

  // ds_read physical offsets; swizzle mask is independent of m/n so fragment
  // strides stay +1024B (compile-time ds offsets).
  const int aoff0 = swzF((wr * 128 + fr) * 64 + fq * 16);
  const int boff0 = ACH + swzF((wc * NF * 16 + fr) * 64 + fq * 16);

  f32x4 acc[8][NF];
#pragma unroll
  for (int m = 0; m < 8; m++)
#pragma unroll
    for (int n = 0; n < NF; n++) acc[m][n] = (f32x4){0.f, 0.f, 0.f, 0.f};

  auto stage = [&](int p) {
    char* s = &lds[(p & 3) * CH];
    const int ktB = p * 64;
    gload16(Ag + Abase + (size_t)(offA[0] + ktB), s + dstA[0]);
    gload16(Ag + Abase + (size_t)(offA[1] + ktB), s + dstA[1]);
    gload16(Bg + Bbase + (size_t)(offB[0] + ktB), s + dstB[0]);
    if constexpr (NF == 4)
      gload16(Bg + Bbase + (size_t)(offB[1] + ktB), s + dstB[1]);
  };

  f16x8 a0[8], b0[NF], a1[8], b1[NF];

  // prologue: chunks 0,1 staged; confirm 0, read it into set 0
  stage(0);
  stage(1);
  __builtin_amdgcn_sched_barrier(0);
  if constexpr (NF == 4) { asm volatile("s_waitcnt vmcnt(4)"); }
  else                   { asm volatile("s_waitcnt vmcnt(3)"); }
  __builtin_amdgcn_sched_barrier(0);
  __builtin_amdgcn_s_barrier();
  __builtin_amdgcn_sched_barrier(0);
  {
    const char* s0 = &lds[0];
#pragma unroll
    for (int m = 0; m < 8; m++)
      a0[m] = *(const f16x8*)(s0 + aoff0 + m * 1024);
#pragma unroll
    for (int n = 0; n < NF; n++)
      b0[n] = *(const f16x8*)(s0 + boff0 + n * 1024);
  }

#define STEADY_PHASE(P, CA, CB, NA, NB)                                      \
  do {                                                                       \
    stage((P) + 2);                                                          \
    __builtin_amdgcn_sched_barrier(0);                                       \
    if constexpr (NF == 4) { asm volatile("s_waitcnt vmcnt(4)"); }           \
    else                   { asm volatile("s_waitcnt vmcnt(3)"); }           \
    __builtin_amdgcn_sched_barrier(0);                                       \
    __builtin_amdgcn_s_barrier();                                            \
    __builtin_amdgcn_sched_barrier(0);                                       \
    {                                                                        \
      const char* sn = &lds[(((P) + 1) & 3) * CH];                           \
      _Pragma("unroll") for (int m = 0; m < 8; m++)                          \
          NA[m] = *(const f16x8*)(sn + aoff0 + m * 1024);                    \
      _Pragma("unroll") for (int n = 0; n < NF; n++)                         \
          NB[n] = *(const f16x8*)(sn + boff0 + n * 1024);                    \
    }                                                                        \
    __builtin_amdgcn_s_setprio(1);                                           \
    _Pragma("unroll") for (int m = 0; m < 8; m++)                            \
      _Pragma("unroll") for (int n = 0; n < NF; n++)                         \
        acc[m][n] = __builtin_amdgcn_mfma_f32_16x16x32_f16(                  \
            CA[m], CB[n], acc[m][n], 0, 0, 0);                               \
    __builtin_amdgcn_s_setprio(0);                                           \
    __builtin_amdgcn_sched_barrier(0);                                       \
  } while (0)

  for (int P = 0; P < NP - 2; P += 2) {
    STEADY_PHASE(P, a0, b0, a1, b1);
    STEADY_PHASE(P + 1, a1, b1, a0, b0);
  }
#undef STEADY_PHASE

  // tail phase NP-2: retire stage(NP-1), read chunk NP-1, MFMA chunk NP-2
  asm volatile("s_waitcnt vmcnt(0)");
  __builtin_amdgcn_sched_barrier(0);
  __builtin_amdgcn_s_barrier();
  __builtin_amdgcn_sched_barrier(0);
  {
    const char* sn = &lds[((NP - 1) & 3) * CH];
#pragma unroll
    for (int m = 0; m < 8; m++)
      a1[m] = *(const f16x8*)(sn + aoff0 + m * 1024);
#pragma unroll
    for (int n = 0; n < NF; n++)
      b1[n] = *(const f16x8*)(sn + boff0 + n * 1024);
  }
  __builtin_amdgcn_s_setprio(1);
#pragma unroll
  for (int m = 0; m < 8; m++)
#pragma unroll
    for (int n = 0; n < NF; n++)
      acc[m][n] = __builtin_amdgcn_mfma_f32_16x16x32_f16(a0[m], b0[n],
                                                         acc[m][n], 0, 0, 0);
  // final phase NP-1: MFMA on set 1 (regs already loaded)
#pragma unroll
  for (int m = 0; m < 8; m++)
#pragma unroll
    for (int n = 0; n < NF; n++)
      acc[m][n] = __builtin_amdgcn_mfma_f32_16x16x32_f16(a1[m], b1[n],
                                                         acc[m][n], 0, 0, 0);
  __builtin_amdgcn_s_setprio(0);

#pragma unroll
  for (int m = 0; m < 8; m++) {
    const size_t row0 = bm + wr * 128 + m * 16 + fq * 4;
#pragma unroll
    for (int n = 0; n < NF; n++) {
      const size_t col = bn + wc * NF * 16 + n * 16 + fr;
      float bcol = (BIAS_MODE == 1) ? bias[col] : 0.f;
#pragma unroll
      for (int r = 0; r < 4; r++) {
        float val = acc[m][n][r];
        const size_t row = row0 + r;
        const size_t idx = row * (size_t)ldc + col;
        if (BIAS_MODE == 1) val += bcol;
        if (BIAS_MODE == 2) val += bias[row];
        if (RES) val += res[idx];
        if (OMODE == 0)
          ((float*)Cb)[idx] = val;
        else
          ((short*)Cb)[idx] = f2h(val);
      }
    }
  }
}

__global__ __launch_bounds__(256) void cvt_f32_f16(const float* __restrict__ s,
                                                   short* __restrict__ d, int n) {
  int i = (blockIdx.x * 256 + threadIdx.x) * 8;
  if (i >= n) return;
  const float4 a = *(const float4*)(s + i);
  const float4 b = *(const float4*)(s + i + 4);
  bf16x8 o;
  o[0] = f2h(a.x); o[1] = f2h(a.y); o[2] = f2h(a.z); o[3] = f2h(a.w);
  o[4] = f2h(b.x); o[5] = f2h(b.y); o[6] = f2h(b.z); o[7] = f2h(b.w);
  *(bf16x8*)(d + i) = o;
}

// one block per row of 4096 f16 scores; fp32 softmax; in-place f16 probs
__global__ __launch_bounds__(256) void softmax_rows(short* __restrict__ S) {
  const size_t row = blockIdx.x;
  short* rp = S + row * 4096;
  const int tid = threadIdx.x;
  const int lane = tid & 63, wid = tid >> 6;
  float v[16];
#pragma unroll
  for (int c = 0; c < 2; c++) {
    bf16x8 xv = *(const bf16x8*)(rp + (c * 256 + tid) * 8);
#pragma unroll
    for (int j = 0; j < 8; j++) v[c * 8 + j] = h2f(xv[j]);
  }
  float m = v[0];
#pragma unroll
  for (int i = 1; i < 16; i++) m = fmaxf(m, v[i]);
#pragma unroll
  for (int off = 32; off >= 1; off >>= 1) m = fmaxf(m, __shfl_xor(m, off));
  __shared__ float red[8];
  if (lane == 0) red[wid] = m;
  __syncthreads();
  m = fmaxf(fmaxf(red[0], red[1]), fmaxf(red[2], red[3]));
  float s = 0.f;
#pragma unroll
  for (int i = 0; i < 16; i++) {
    v[i] = __expf(v[i] - m);
    s += v[i];
  }
#pragma unroll
  for (int off = 32; off >= 1; off >>= 1) s += __shfl_xor(s, off);
  if (lane == 0) red[4 + wid] = s;
  __syncthreads();
  s = (red[4] + red[5]) + (red[6] + red[7]);
  const float rs = 1.0f / s;
#pragma unroll
  for (int c = 0; c < 2; c++) {
    bf16x8 o;
#pragma unroll
    for (int j = 0; j < 8; j++) o[j] = f2h(v[c * 8 + j] * rs);
    *(bf16x8*)(rp + (c * 256 + tid) * 8) = o;
  }
}

extern "C" void kernel_launch(void* const* d_in, const int* in_sizes, int n_in,
                              void* d_out, int out_size, void* d_ws,
                              size_t ws_size, hipStream_t stream) {
  const float* x   = (const float*)d_in[0];
  const float* thw = (const float*)d_in[1];
  const float* thb = (const float*)d_in[2];
  const float* phw = (const float*)d_in[3];
  const float* phb = (const float*)d_in[4];
  const float* gw  = (const float*)d_in[5];
  const float* gbi = (const float*)d_in[6];
  const float* Ww  = (const float*)d_in[7];
  const float* Wb  = (const float*)d_in[8];
  float* out = (float*)d_out;

  // B=4, N=4096, D=2048, E=1024.  ws footprint 184,557,568 B (proven size)
  char* ws = (char*)d_ws;
  short* xf   = (short*)(ws);                // 67,108,864 B (16384x2048 f16)
  short* wcat = (short*)(ws + 67108864);     //  8,388,608 B (theta|phi 2048x2048)
  short* gwb  = (short*)(ws + 75497472);     //  4,194,304 B (1024x2048)
  short* wWb  = (short*)(ws + 79691776);     //  4,194,304 B (2048x1024)
  float* bc   = (float*)(ws + 83886080);     //  8,192 B (theta_b|phi_b)
  short* tpf  = (short*)(ws + 83894272);     // 67,108,864 B (theta|phi; later y)
  short* gT   = (short*)(ws + 151003136);    // 33,554,432 B (4x1024x4096)
  short* sc   = (short*)(ws);                // 67,108,864 B (2x4096x4096, over xf)

  // 1) fp32 -> f16 conversions
  cvt_f32_f16<<<16384, 256, 0, stream>>>(x, xf, 33554432);
  cvt_f32_f16<<<1024, 256, 0, stream>>>(thw, wcat, 2097152);
  cvt_f32_f16<<<1024, 256, 0, stream>>>(phw, wcat + 2097152, 2097152);
  cvt_f32_f16<<<1024, 256, 0, stream>>>(gw, gwb, 2097152);
  cvt_f32_f16<<<1024, 256, 0, stream>>>(Ww, wWb, 2097152);
  hipMemcpyAsync(bc, thb, 4096, hipMemcpyDeviceToDevice, stream);
  hipMemcpyAsync(bc + 1024, phb, 4096, hipMemcpyDeviceToDevice, stream);

  // 2) proj: [theta|phi] = x @ wcat^T + bias   (16384 x 2048, K=2048)
  gemmp<4, 2048, 1, 1, 0><<<dim3(8, 64, 1), 512, 0, stream>>>(
      xf, 2048, 0L, wcat, 2048, 0L, tpf, 2048, 0L, bc, nullptr, 0L);

  // 3) gT[b] = g_w @ x_b^T + g_b[row]   (1024 x 4096 per batch, K=2048)
  gemmp<4, 2048, 1, 2, 0><<<dim3(16, 4, 4), 512, 0, stream>>>(
      gwb, 2048, 0L, xf, 2048, 8388608L, gT, 4096, 4194304L, gbi, nullptr, 0L);

  // 4) per batch-PAIR p: scores(z=2) -> softmax -> y(z=2) -> z(z=2)
  //    sc pair overlays xf (dead after gT); y overwrites consumed theta/phi.
  for (int p = 0; p < 2; ++p) {
    const short* tp = tpf + (size_t)p * 16777216;
    gemmp<4, 1024, 1, 0, 0><<<dim3(16, 16, 2), 512, 0, stream>>>(
        tp, 2048, 8388608L, tp + 1024, 2048, 8388608L,
        sc, 4096, 16777216L, nullptr, nullptr, 0L);
    softmax_rows<<<8192, 256, 0, stream>>>(sc);
    short* yp = tpf + (size_t)p * 16777216;  // pair-p theta/phi now dead
    gemmp<2, 4096, 1, 0, 0><<<dim3(8, 16, 2), 512, 0, stream>>>(
        sc, 4096, 16777216L, gT + (size_t)p * 8388608, 4096, 4194304L,
        yp, 1024, 4194304L, nullptr, nullptr, 0L);
    gemmp<4, 1024, 0, 1, 1><<<dim3(8, 16, 2), 512, 0, stream>>>(
        yp, 1024, 4194304L, wWb, 1024, 0L,
        out + (size_t)p * 16777216, 2048, 8388608L,
        Wb, x + (size_t)p * 16777216, 8388608L);
  }
}